// Round 3
// baseline (509.573 us; speedup 1.0000x reference)
//
#include <hip/hip_runtime.h>

typedef __attribute__((ext_vector_type(8))) short short8_t;
typedef __attribute__((ext_vector_type(4))) float float4_t;

__device__ __forceinline__ unsigned short f2bf(float f) {
    unsigned int u = __float_as_uint(f);
    return (unsigned short)((u + 0x7FFFu + ((u >> 16) & 1u)) >> 16);
}
__device__ __forceinline__ unsigned int pkbf(float a, float b) {
    return (unsigned int)f2bf(a) | ((unsigned int)f2bf(b) << 16);
}

// ---------------------------------------------------------------------------
// K0: one-shot w1 fp32 -> bf16 ([256][4096] row-major).
// ---------------------------------------------------------------------------
__global__ __launch_bounds__(256) void k_wprep(
    const float* __restrict__ w1, unsigned short* __restrict__ w1s)
{
    const int id = blockIdx.x * 256 + threadIdx.x;   // 131072, 8 floats each
    const float4* s = (const float4*)(w1 + id * 8);
    float4 a = s[0], b = s[1];
    int4 o;
    o.x = pkbf(a.x, a.y); o.y = pkbf(a.z, a.w);
    o.z = pkbf(b.x, b.y); o.w = pkbf(b.z, b.w);
    *(int4*)(w1s + id * 8) = o;
}

// ---------------------------------------------------------------------------
// K1: conv1 implicit GEMM, 512-thread proven structure (128M x 256N, BK=32,
// split-K x4, 8 waves 2m x 4n). CHANGE vs r2: register prefetch depth 2 —
// loads for iter i are issued during iter i-2's MFMA phase (~1200 cyc in
// flight > 900 cyc HBM latency), so the LDS-commit no longer stalls on vmcnt.
// A-LDS XOR swizzle on k-slot, matching fragment read.
// ---------------------------------------------------------------------------
#define CONV_LOAD_A(dst, k0q) {                                               \
    const int ic = (k0q) >> 6, kh0 = ((k0q) >> 3) & 7;                        \
    const int xr = (oh0 + ohl) * 8 + kh0 + khl;                               \
    const float4* s4 = (const float4*)(x + (((bi * 64 + ic) * 256 + xr) * 256 + segA * 16)); \
    dst[0] = s4[0]; dst[1] = s4[1]; dst[2] = s4[2]; dst[3] = s4[3];           \
}
#define CONV_LOAD_B(dst, k0q) {                                               \
    _Pragma("unroll")                                                         \
    for (int l = 0; l < 4; ++l) {                                             \
        const int slot = l * 256 + tA;                                        \
        const int row = slot >> 2, p = slot & 3;                              \
        dst[l] = *(const int4*)(w1s + row * 4096 + (k0q) + p * 8);            \
    }                                                                         \
}
#define CONV_COMMIT_A(src) {                                                  \
    int4 p0, p1;                                                              \
    p0.x = pkbf(src[0].x, src[0].y); p0.y = pkbf(src[0].z, src[0].w);         \
    p0.z = pkbf(src[1].x, src[1].y); p0.w = pkbf(src[1].z, src[1].w);         \
    p1.x = pkbf(src[2].x, src[2].y); p1.y = pkbf(src[2].z, src[2].w);         \
    p1.z = pkbf(src[3].x, src[3].y); p1.w = pkbf(src[3].z, src[3].w);         \
    *(int4*)&At[rowA * 40 + koffA] = p0;                                      \
    *(int4*)&At[(rowA + 1) * 40 + koffA] = p1;                                \
}
#define CONV_COMMIT_B(src) {                                                  \
    _Pragma("unroll")                                                         \
    for (int l = 0; l < 4; ++l) {                                             \
        const int slot = l * 256 + tA;                                        \
        const int row = slot >> 2, p = slot & 3;                              \
        *(int4*)&Bt[row * 40 + p * 8] = src[l];                               \
    }                                                                         \
}
#define CONV_MFMA() {                                                         \
    short8_t aF[4], bF[4];                                                    \
    _Pragma("unroll")                                                         \
    for (int i = 0; i < 4; ++i) {                                             \
        const int R = wm * 64 + i * 16 + r16;                                 \
        aF[i] = *(const short8_t*)&At[R * 40 + (quad ^ ((r16 >> 1) & 3)) * 8];\
    }                                                                         \
    _Pragma("unroll")                                                         \
    for (int j = 0; j < 4; ++j)                                               \
        bF[j] = *(const short8_t*)&Bt[(wn * 64 + j * 16 + r16) * 40 + quad * 8]; \
    _Pragma("unroll")                                                         \
    for (int i = 0; i < 4; ++i)                                               \
        _Pragma("unroll")                                                     \
        for (int j = 0; j < 4; ++j)                                           \
            acc[i][j] = __builtin_amdgcn_mfma_f32_16x16x32_bf16(aF[i], bF[j], acc[i][j], 0, 0, 0); \
}

__global__ __launch_bounds__(512, 2) void k_conv1(
    const float* __restrict__ x, const unsigned short* __restrict__ w1s,
    float* __restrict__ part)
{
    __shared__ unsigned short At[128 * 40];
    __shared__ unsigned short Bt[256 * 40];
    const int tid = threadIdx.x;
    const int mt = blockIdx.x, kc = blockIdx.y;
    const int m0 = mt * 128;
    const int bi = mt >> 3;
    const int oh0 = (mt & 7) * 4;
    const int lane = tid & 63, wid = tid >> 6;
    const int wm = wid & 1, wn = wid >> 1;          // 2 x 4 waves
    const int quad = lane >> 4, r16 = lane & 15;
    const bool isA = tid < 256;
    const int tA = tid & 255;
    const int rA = tA >> 4, segA = tA & 15;
    const int ohl = rA >> 2, khl = rA & 3;
    const int rowA = ohl * 32 + segA * 2;
    const int koffA = (khl ^ (segA & 3)) * 8;       // swizzled k-slot (shorts)
    const int kbase = kc * 1024;
    float4_t acc[4][4] = {};
    float4 raA[4], raB[4];   // A prefetch regs, depth 2
    int4 rbA[4], rbB[4];     // B prefetch regs, depth 2

    // prefetch iters 0 and 1
    if (isA) { CONV_LOAD_A(raA, kbase); CONV_LOAD_A(raB, kbase + 32); }
    else     { CONV_LOAD_B(rbA, kbase); CONV_LOAD_B(rbB, kbase + 32); }

    for (int it = 0; it < 32; it += 2) {
        // ---- even iter: consume set A ----
        if (isA) CONV_COMMIT_A(raA) else CONV_COMMIT_B(rbA);
        __syncthreads();
        if (it + 2 < 32) {
            const int k0 = kbase + (it + 2) * 32;
            if (isA) CONV_LOAD_A(raA, k0) else CONV_LOAD_B(rbA, k0);
        }
        CONV_MFMA();
        __syncthreads();
        // ---- odd iter: consume set B ----
        if (isA) CONV_COMMIT_A(raB) else CONV_COMMIT_B(rbB);
        __syncthreads();
        if (it + 3 < 32) {
            const int k0 = kbase + (it + 3) * 32;
            if (isA) CONV_LOAD_A(raB, k0) else CONV_LOAD_B(rbB, k0);
        }
        CONV_MFMA();
        __syncthreads();
    }
    float* pp = part + ((size_t)kc << 21);
    #pragma unroll
    for (int i = 0; i < 4; ++i) {
        const int mg = m0 + wm * 64 + i * 16 + quad * 4;
        #pragma unroll
        for (int j = 0; j < 4; ++j) {
            const int ng = wn * 64 + j * 16 + r16;
            #pragma unroll
            for (int r = 0; r < 4; ++r)
                pp[(mg + r) * 256 + ng] = acc[i][j][r];
        }
    }
}

// ---------------------------------------------------------------------------
// K1b: reduce 4 split-K partials + BN + ReLU -> y bf16 [8192,256]. (unchanged)
// ---------------------------------------------------------------------------
__global__ __launch_bounds__(256, 4) void k_reduce(
    const float* __restrict__ part, const float* __restrict__ s1,
    const float* __restrict__ b1, unsigned short* __restrict__ y)
{
    const int id = blockIdx.x * 256 + threadIdx.x;   // 0..524287 float4 slots
    const int c4 = id & 63;
    const float4* p = (const float4*)part + id;
    float4 a = p[0], b = p[524288], c = p[1048576], d = p[1572864];
    float4 s = ((const float4*)s1)[c4], bb = ((const float4*)b1)[c4];
    float vx = fmaxf((a.x + b.x + c.x + d.x) * s.x + bb.x, 0.f);
    float vy = fmaxf((a.y + b.y + c.y + d.y) * s.y + bb.y, 0.f);
    float vz = fmaxf((a.z + b.z + c.z + d.z) * s.z + bb.z, 0.f);
    float vw = fmaxf((a.w + b.w + c.w + d.w) * s.w + bb.w, 0.f);
    int2 o; o.x = pkbf(vx, vy); o.y = pkbf(vz, vw);
    ((int2*)y)[id] = o;
}

// ---------------------------------------------------------------------------
// K2: fused fai/sit/gama projections. (unchanged)
// nt<4 -> P bf16 [8192,256] (cols 0-127 fai, 128-255 sit);
// nt>=4 -> G bf16 [8,128,1024] (transposed, AV GEMM B-operand).
// ---------------------------------------------------------------------------
__global__ __launch_bounds__(256, 2) void k_proj3(
    const unsigned short* __restrict__ y,
    const float* __restrict__ w_fai, const float* __restrict__ w_sit,
    const float* __restrict__ w_gama,
    const float* __restrict__ fs, const float* __restrict__ fb,
    const float* __restrict__ ss, const float* __restrict__ sb,
    const float* __restrict__ gs, const float* __restrict__ gb,
    unsigned short* __restrict__ P, unsigned short* __restrict__ G)
{
    __shared__ unsigned short At[64 * 40];
    __shared__ unsigned short Bt[64 * 40];
    const int tid = threadIdx.x;
    const int nt = blockIdx.x, mt = blockIdx.y;
    const int m0 = mt * 64;
    const float *W, *S, *Bb;
    if (nt < 2)      { W = w_fai;  S = fs; Bb = fb; }
    else if (nt < 4) { W = w_sit;  S = ss; Bb = sb; }
    else             { W = w_gama; S = gs; Bb = gb; }
    const int roff = (nt * 64) & 127;
    const int lane = tid & 63, wid = tid >> 6;
    const int wm = wid & 1, wn = wid >> 1;
    const int quad = lane >> 4, r16 = lane & 15;
    float4_t acc[2][2] = {};

    for (int k0 = 0; k0 < 256; k0 += 32) {
        {   // A: y tile 64x32 bf16, direct copy
            const int row = tid >> 2, pp = tid & 3;
            *(int4*)&At[row * 40 + pp * 8] =
                *(const int4*)(y + (m0 + row) * 256 + k0 + pp * 8);
        }
        #pragma unroll
        for (int l = 0; l < 2; ++l) {   // B: W tile 64x32 fp32 -> bf16
            const int slot = l * 256 + tid;
            const int row = slot >> 3, pp = slot & 7;
            float4 v = *(const float4*)(W + (roff + row) * 256 + k0 + pp * 4);
            int2 wv; wv.x = pkbf(v.x, v.y); wv.y = pkbf(v.z, v.w);
            *(int2*)&Bt[row * 40 + pp * 4] = wv;
        }
        __syncthreads();
        short8_t aF[2], bF[2];
        #pragma unroll
        for (int i = 0; i < 2; ++i)
            aF[i] = *(const short8_t*)&At[(wm * 32 + i * 16 + r16) * 40 + quad * 8];
        #pragma unroll
        for (int j = 0; j < 2; ++j)
            bF[j] = *(const short8_t*)&Bt[(wn * 32 + j * 16 + r16) * 40 + quad * 8];
        #pragma unroll
        for (int i = 0; i < 2; ++i)
            #pragma unroll
            for (int j = 0; j < 2; ++j)
                acc[i][j] = __builtin_amdgcn_mfma_f32_16x16x32_bf16(aF[i], bF[j], acc[i][j], 0, 0, 0);
        __syncthreads();
    }
    #pragma unroll
    for (int i = 0; i < 2; ++i) {
        const int mg = m0 + wm * 32 + i * 16 + quad * 4;
        #pragma unroll
        for (int j = 0; j < 2; ++j) {
            const int nl = wn * 32 + j * 16 + r16;
            const float sc = S[roff + nl], bc = Bb[roff + nl];
            if (nt < 4) {
                const int col = nt * 64 + nl;
                #pragma unroll
                for (int r = 0; r < 4; ++r) {
                    float v = fmaxf(acc[i][j][r] * sc + bc, 0.f);
                    P[(mg + r) * 256 + col] = f2bf(v);
                }
            } else {
                const int c = roff + nl;
                #pragma unroll
                for (int r = 0; r < 4; ++r) {
                    float v = fmaxf(acc[i][j][r] * sc + bc, 0.f);
                    const int sp = mg + r;
                    G[((sp >> 10) * 128 + c) * 1024 + (sp & 1023)] = f2bf(v);
                }
            }
        }
    }
}

// ---------------------------------------------------------------------------
// K3+K4 fused: k_attn. CHANGE vs r2: async-STAGE split (T14) — G-tile loads
// are issued into registers BEFORE GEMM1 and committed to LDS after its
// barrier; sit(ms=1) loads are issued before GEMM2. Staging latency now hides
// under the adjacent MFMA phases instead of serializing between barriers.
// Grid (16 nt, 32 = b*4+kc). Partials Opart[kc][8][1024][128] fp32.
// ---------------------------------------------------------------------------
#define LSTR 152
__global__ __launch_bounds__(256, 2) void k_attn(
    const unsigned short* __restrict__ P, const unsigned short* __restrict__ G,
    float* __restrict__ Opart)
{
    __shared__ unsigned short At[64 * LSTR];    // fai tile [64 n][128 c]
    __shared__ unsigned short Bt[128 * LSTR];   // sit tile, then G tile
    __shared__ unsigned short Sl[64 * LSTR];    // sigma(S) [64 n][128 m]
    const int tid = threadIdx.x;
    const int nt = blockIdx.x, zz = blockIdx.y;
    const int b = zz >> 2, kc = zz & 3;
    const int n0 = nt * 64;
    const int base = b * 1024;
    const int lane = tid & 63, wid = tid >> 6;
    const int wm = wid & 1, wn = wid >> 1;
    const int quad = lane >> 4, r16 = lane & 15;
    const int srow = tid >> 4, sp16 = tid & 15;     // staging row/seg (16B units)
    float4_t acc2[2][4] = {};
    int4 rs[8], rg[8];

    // stage fai tile (direct), issue sit(ms=0) loads into rs
    #pragma unroll
    for (int l = 0; l < 4; ++l) {
        const int slot = l * 256 + tid;
        const int row = slot >> 4, p = slot & 15;
        *(int4*)&At[row * LSTR + p * 8] =
            *(const int4*)(P + (base + n0 + row) * 256 + p * 8);
    }
    {
        const int m1 = kc * 256;
        #pragma unroll
        for (int l = 0; l < 8; ++l)
            rs[l] = *(const int4*)(P + (base + m1 + (l * 16 + srow)) * 256 + 128 + sp16 * 8);
    }
    #pragma unroll
    for (int ms = 0; ms < 2; ++ms) {
        const int m1 = kc * 256 + ms * 128;
        // commit sit tile [128 m][128 c] from regs
        #pragma unroll
        for (int l = 0; l < 8; ++l)
            *(int4*)&Bt[(l * 16 + srow) * LSTR + sp16 * 8] = rs[l];
        __syncthreads();
        // issue G(ms) loads -> rg (consumed after GEMM1's barrier)
        #pragma unroll
        for (int l = 0; l < 8; ++l)
            rg[l] = *(const int4*)(G + (b * 128 + (l * 16 + srow)) * 1024 + m1 + sp16 * 8);
        // GEMM1: S[n,m], wave tile 32(n) x 64(m)
        float4_t acc1[2][4] = {};
        #pragma unroll
        for (int c = 0; c < 4; ++c) {
            short8_t aF[2], bF[4];
            #pragma unroll
            for (int i = 0; i < 2; ++i)
                aF[i] = *(const short8_t*)&At[(wm * 32 + i * 16 + r16) * LSTR + c * 32 + quad * 8];
            #pragma unroll
            for (int j = 0; j < 4; ++j)
                bF[j] = *(const short8_t*)&Bt[(wn * 64 + j * 16 + r16) * LSTR + c * 32 + quad * 8];
            #pragma unroll
            for (int i = 0; i < 2; ++i)
                #pragma unroll
                for (int j = 0; j < 4; ++j)
                    acc1[i][j] = __builtin_amdgcn_mfma_f32_16x16x32_bf16(aF[i], bF[j], acc1[i][j], 0, 0, 0);
        }
        __syncthreads();   // Bt(sit) reads done
        // sigmoid -> Sl (LDS only)
        #pragma unroll
        for (int i = 0; i < 2; ++i) {
            const int nl = wm * 32 + i * 16 + quad * 4;
            #pragma unroll
            for (int j = 0; j < 4; ++j) {
                const int ml = wn * 64 + j * 16 + r16;
                #pragma unroll
                for (int r = 0; r < 4; ++r) {
                    const float xv = acc1[i][j][r];
                    const float e = __expf(-xv);
                    const float v = __builtin_amdgcn_rcpf(1.0f + e);
                    Sl[(nl + r) * LSTR + ml] = f2bf(v);
                }
            }
        }
        // commit G tile [128 ch][128 m] from regs
        #pragma unroll
        for (int l = 0; l < 8; ++l)
            *(int4*)&Bt[(l * 16 + srow) * LSTR + sp16 * 8] = rg[l];
        // issue sit(ms=1) loads (consumed next iteration, after GEMM2)
        if (ms == 0) {
            const int m1n = kc * 256 + 128;
            #pragma unroll
            for (int l = 0; l < 8; ++l)
                rs[l] = *(const int4*)(P + (base + m1n + (l * 16 + srow)) * 256 + 128 + sp16 * 8);
        }
        __syncthreads();   // Sl + Bt(G) visible
        // GEMM2: O[n,ch] += Sl . G^T, wave tile 32(n) x 64(ch)
        #pragma unroll
        for (int c = 0; c < 4; ++c) {
            short8_t aF[2], bF[4];
            #pragma unroll
            for (int i = 0; i < 2; ++i)
                aF[i] = *(const short8_t*)&Sl[(wm * 32 + i * 16 + r16) * LSTR + c * 32 + quad * 8];
            #pragma unroll
            for (int j = 0; j < 4; ++j)
                bF[j] = *(const short8_t*)&Bt[(wn * 64 + j * 16 + r16) * LSTR + c * 32 + quad * 8];
            #pragma unroll
            for (int i = 0; i < 2; ++i)
                #pragma unroll
                for (int j = 0; j < 4; ++j)
                    acc2[i][j] = __builtin_amdgcn_mfma_f32_16x16x32_bf16(aF[i], bF[j], acc2[i][j], 0, 0, 0);
        }
        __syncthreads();   // before next ms overwrites Bt / Sl
    }
    float* op = Opart + (size_t)kc * 1048576 + (size_t)b * 131072;
    #pragma unroll
    for (int i = 0; i < 2; ++i) {
        const int nl = n0 + wm * 32 + i * 16 + quad * 4;
        #pragma unroll
        for (int j = 0; j < 4; ++j) {
            const int ch = wn * 64 + j * 16 + r16;
            #pragma unroll
            for (int r = 0; r < 4; ++r)
                op[(nl + r) * 128 + ch] = acc2[i][j][r];
        }
    }
}

// ---------------------------------------------------------------------------
// K5: sum 4 O-partials + bilinear x8 upsample (align_corners). (unchanged)
// ---------------------------------------------------------------------------
__global__ __launch_bounds__(256, 2) void k_up(
    const float* __restrict__ Opart, float* __restrict__ out)
{
    __shared__ float l0[32 * 136];
    __shared__ float l1[32 * 136];
    const int tid = threadIdx.x;
    const int yb = blockIdx.x, b = blockIdx.y;
    const float sc = 31.0f / 255.0f;
    const float fy = yb * sc;
    const int y0 = (int)fy;
    const float wy = fy - (float)y0;
    const int y1 = (y0 + 1 < 32) ? y0 + 1 : 31;
    const float4* r0 = (const float4*)(Opart + (size_t)b * 131072 + y0 * 4096);
    const float4* r1 = (const float4*)(Opart + (size_t)b * 131072 + y1 * 4096);
    #pragma unroll
    for (int j = 0; j < 4; ++j) {
        const int id = j * 256 + tid;       // 0..1023 float4 chunks of a row
        const int xs = id >> 5, c4 = id & 31;
        float4 a0 = r0[id], a1 = r1[id];
        #pragma unroll
        for (int kc = 1; kc < 4; ++kc) {
            float4 t0 = r0[id + kc * 262144], t1 = r1[id + kc * 262144];
            a0.x += t0.x; a0.y += t0.y; a0.z += t0.z; a0.w += t0.w;
            a1.x += t1.x; a1.y += t1.y; a1.z += t1.z; a1.w += t1.w;
        }
        *(float4*)(l0 + xs * 136 + c4 * 4) = a0;
        *(float4*)(l1 + xs * 136 + c4 * 4) = a1;
    }
    __syncthreads();
    const float fx = tid * sc;
    const int x0 = (int)fx;
    const float wx = fx - (float)x0;
    const int x1 = (x0 + 1 < 32) ? x0 + 1 : 31;
    const float w00 = (1.f - wy) * (1.f - wx), w01 = (1.f - wy) * wx;
    const float w10 = wy * (1.f - wx), w11 = wy * wx;
    const float* a = l0 + x0 * 136;
    const float* bq = l0 + x1 * 136;
    const float* c = l1 + x0 * 136;
    const float* d = l1 + x1 * 136;
    float* op = out + (size_t)b * 8388608 + yb * 256 + tid;
    #pragma unroll 4
    for (int ch = 0; ch < 128; ++ch)
        op[ch * 65536] = w00 * a[ch] + w01 * bq[ch] + w10 * c[ch] + w11 * d[ch];
}

extern "C" void kernel_launch(void* const* d_in, const int* in_sizes, int n_in,
                              void* d_out, int out_size, void* d_ws, size_t ws_size,
                              hipStream_t stream) {
    (void)in_sizes; (void)n_in; (void)out_size; (void)ws_size;
    const float* x      = (const float*)d_in[0];
    const float* w1     = (const float*)d_in[1];
    const float* bn1_s  = (const float*)d_in[2];
    const float* bn1_b  = (const float*)d_in[3];
    const float* w_fai  = (const float*)d_in[4];
    const float* bnf_s  = (const float*)d_in[5];
    const float* bnf_b  = (const float*)d_in[6];
    const float* w_sit  = (const float*)d_in[7];
    const float* bns_s  = (const float*)d_in[8];
    const float* bns_b  = (const float*)d_in[9];
    const float* w_gama = (const float*)d_in[10];
    const float* bng_s  = (const float*)d_in[11];
    const float* bng_b  = (const float*)d_in[12];
    float* out = (float*)d_out;

    char* ws = (char*)d_ws;
    // [0,32MB): conv partials pc; after k_reduce the region is reused:
    //   Opart @ 16MB (16 MB, k_attn partials)
    float*          pc    = (float*)ws;                                 // [4][8192][256]
    float*          Opart = (float*)(ws + 16u * 1024 * 1024);           // [4][8][1024][128]
    unsigned short* y     = (unsigned short*)(ws + 32u * 1024 * 1024);  // 4 MB
    unsigned short* P     = (unsigned short*)(ws + 36u * 1024 * 1024);  // 4 MB
    unsigned short* G     = (unsigned short*)(ws + 40u * 1024 * 1024);  // 2 MB
    unsigned short* w1s   = (unsigned short*)(ws + 44u * 1024 * 1024);  // 2 MB

    k_wprep <<<dim3(512),      256, 0, stream>>>(w1, w1s);
    k_conv1 <<<dim3(64, 4),    512, 0, stream>>>(x, w1s, pc);
    k_reduce<<<dim3(2048),     256, 0, stream>>>(pc, bn1_s, bn1_b, y);
    k_proj3 <<<dim3(6, 128),   256, 0, stream>>>(y, w_fai, w_sit, w_gama,
                                                 bnf_s, bnf_b, bns_s, bns_b,
                                                 bng_s, bng_b, P, G);
    k_attn  <<<dim3(16, 32),   256, 0, stream>>>(P, G, Opart);
    k_up    <<<dim3(256, 8),   256, 0, stream>>>(Opart, out);
}

// Round 5
// 496.646 us; speedup vs baseline: 1.0260x; 1.0260x over previous
//
#include <hip/hip_runtime.h>

typedef __attribute__((ext_vector_type(8))) short short8_t;
typedef __attribute__((ext_vector_type(4))) float float4_t;

__device__ __forceinline__ unsigned short f2bf(float f) {
    unsigned int u = __float_as_uint(f);
    return (unsigned short)((u + 0x7FFFu + ((u >> 16) & 1u)) >> 16);
}
__device__ __forceinline__ unsigned int pkbf(float a, float b) {
    return (unsigned int)f2bf(a) | ((unsigned int)f2bf(b) << 16);
}

// Barrier that does NOT drain vmcnt: LDS ordering is fully protected
// (lgkmcnt(0) before s_barrier), but global loads into registers stay in
// flight across the barrier. __syncthreads() would force vmcnt(0) and
// serialize every prefetch (the m97 barrier-drain stall).
#define BARRIER_LGKM() asm volatile("s_waitcnt lgkmcnt(0)\ns_barrier" ::: "memory")

// ---------------------------------------------------------------------------
// K0: one-shot w1 fp32 -> bf16 ([256][4096] row-major).
// ---------------------------------------------------------------------------
__global__ __launch_bounds__(256) void k_wprep(
    const float* __restrict__ w1, unsigned short* __restrict__ w1s)
{
    const int id = blockIdx.x * 256 + threadIdx.x;   // 131072, 8 floats each
    const float4* s = (const float4*)(w1 + id * 8);
    float4 a = s[0], b = s[1];
    int4 o;
    o.x = pkbf(a.x, a.y); o.y = pkbf(a.z, a.w);
    o.z = pkbf(b.x, b.y); o.w = pkbf(b.z, b.w);
    *(int4*)(w1s + id * 8) = o;
}

// ---------------------------------------------------------------------------
// K1: conv1 implicit GEMM, 512-thread structure (128M x 256N, BK=32,
// split-K x4, 8 waves 2m x 4n). Register prefetch depth 2 + lgkm-only
// barriers: loads for iter i are issued during iter i-2 and now genuinely
// stay in flight across the two intervening barriers (~2 phases of latency
// coverage), instead of being drained by __syncthreads' vmcnt(0).
// A-LDS XOR swizzle on k-slot, matching fragment read.
// ---------------------------------------------------------------------------
#define CONV_LOAD_A(dst, k0q) {                                               \
    const int ic = (k0q) >> 6, kh0 = ((k0q) >> 3) & 7;                        \
    const int xr = (oh0 + ohl) * 8 + kh0 + khl;                               \
    const float4* s4 = (const float4*)(x + (((bi * 64 + ic) * 256 + xr) * 256 + segA * 16)); \
    dst[0] = s4[0]; dst[1] = s4[1]; dst[2] = s4[2]; dst[3] = s4[3];           \
}
#define CONV_LOAD_B(dst, k0q) {                                               \
    _Pragma("unroll")                                                         \
    for (int l = 0; l < 4; ++l) {                                             \
        const int slot = l * 256 + tA;                                        \
        const int row = slot >> 2, p = slot & 3;                              \
        dst[l] = *(const int4*)(w1s + row * 4096 + (k0q) + p * 8);            \
    }                                                                         \
}
#define CONV_COMMIT_A(src) {                                                  \
    int4 p0, p1;                                                              \
    p0.x = pkbf(src[0].x, src[0].y); p0.y = pkbf(src[0].z, src[0].w);         \
    p0.z = pkbf(src[1].x, src[1].y); p0.w = pkbf(src[1].z, src[1].w);         \
    p1.x = pkbf(src[2].x, src[2].y); p1.y = pkbf(src[2].z, src[2].w);         \
    p1.z = pkbf(src[3].x, src[3].y); p1.w = pkbf(src[3].z, src[3].w);         \
    *(int4*)&At[rowA * 40 + koffA] = p0;                                      \
    *(int4*)&At[(rowA + 1) * 40 + koffA] = p1;                                \
}
#define CONV_COMMIT_B(src) {                                                  \
    _Pragma("unroll")                                                         \
    for (int l = 0; l < 4; ++l) {                                             \
        const int slot = l * 256 + tA;                                        \
        const int row = slot >> 2, p = slot & 3;                              \
        *(int4*)&Bt[row * 40 + p * 8] = src[l];                               \
    }                                                                         \
}
#define CONV_MFMA() {                                                         \
    short8_t aF[4], bF[4];                                                    \
    _Pragma("unroll")                                                         \
    for (int i = 0; i < 4; ++i) {                                             \
        const int R = wm * 64 + i * 16 + r16;                                 \
        aF[i] = *(const short8_t*)&At[R * 40 + (quad ^ ((r16 >> 1) & 3)) * 8];\
    }                                                                         \
    _Pragma("unroll")                                                         \
    for (int j = 0; j < 4; ++j)                                               \
        bF[j] = *(const short8_t*)&Bt[(wn * 64 + j * 16 + r16) * 40 + quad * 8]; \
    _Pragma("unroll")                                                         \
    for (int i = 0; i < 4; ++i)                                               \
        _Pragma("unroll")                                                     \
        for (int j = 0; j < 4; ++j)                                           \
            acc[i][j] = __builtin_amdgcn_mfma_f32_16x16x32_bf16(aF[i], bF[j], acc[i][j], 0, 0, 0); \
}

__global__ __launch_bounds__(512, 2) void k_conv1(
    const float* __restrict__ x, const unsigned short* __restrict__ w1s,
    float* __restrict__ part)
{
    __shared__ unsigned short At[128 * 40];
    __shared__ unsigned short Bt[256 * 40];
    const int tid = threadIdx.x;
    const int mt = blockIdx.x, kc = blockIdx.y;
    const int m0 = mt * 128;
    const int bi = mt >> 3;
    const int oh0 = (mt & 7) * 4;
    const int lane = tid & 63, wid = tid >> 6;
    const int wm = wid & 1, wn = wid >> 1;          // 2 x 4 waves
    const int quad = lane >> 4, r16 = lane & 15;
    const bool isA = tid < 256;
    const int tA = tid & 255;
    const int rA = tA >> 4, segA = tA & 15;
    const int ohl = rA >> 2, khl = rA & 3;
    const int rowA = ohl * 32 + segA * 2;
    const int koffA = (khl ^ (segA & 3)) * 8;       // swizzled k-slot (shorts)
    const int kbase = kc * 1024;
    float4_t acc[4][4] = {};
    float4 raA[4], raB[4];   // A prefetch regs, depth 2
    int4 rbA[4], rbB[4];     // B prefetch regs, depth 2

    // prefetch iters 0 and 1
    if (isA) { CONV_LOAD_A(raA, kbase); CONV_LOAD_A(raB, kbase + 32); }
    else     { CONV_LOAD_B(rbA, kbase); CONV_LOAD_B(rbB, kbase + 32); }

    for (int it = 0; it < 32; it += 2) {
        // ---- even iter: consume set A ----
        if (isA) CONV_COMMIT_A(raA) else CONV_COMMIT_B(rbA);
        BARRIER_LGKM();
        if (it + 2 < 32) {
            const int k0 = kbase + (it + 2) * 32;
            if (isA) CONV_LOAD_A(raA, k0) else CONV_LOAD_B(rbA, k0);
        }
        CONV_MFMA();
        BARRIER_LGKM();
        // ---- odd iter: consume set B ----
        if (isA) CONV_COMMIT_A(raB) else CONV_COMMIT_B(rbB);
        BARRIER_LGKM();
        if (it + 3 < 32) {
            const int k0 = kbase + (it + 3) * 32;
            if (isA) CONV_LOAD_A(raB, k0) else CONV_LOAD_B(rbB, k0);
        }
        CONV_MFMA();
        BARRIER_LGKM();
    }
    float* pp = part + ((size_t)kc << 21);
    #pragma unroll
    for (int i = 0; i < 4; ++i) {
        const int mg = m0 + wm * 64 + i * 16 + quad * 4;
        #pragma unroll
        for (int j = 0; j < 4; ++j) {
            const int ng = wn * 64 + j * 16 + r16;
            #pragma unroll
            for (int r = 0; r < 4; ++r)
                pp[(mg + r) * 256 + ng] = acc[i][j][r];
        }
    }
}

// ---------------------------------------------------------------------------
// K1b: reduce 4 split-K partials + BN + ReLU -> y bf16 [8192,256]. (unchanged)
// ---------------------------------------------------------------------------
__global__ __launch_bounds__(256, 4) void k_reduce(
    const float* __restrict__ part, const float* __restrict__ s1,
    const float* __restrict__ b1, unsigned short* __restrict__ y)
{
    const int id = blockIdx.x * 256 + threadIdx.x;   // 0..524287 float4 slots
    const int c4 = id & 63;
    const float4* p = (const float4*)part + id;
    float4 a = p[0], b = p[524288], c = p[1048576], d = p[1572864];
    float4 s = ((const float4*)s1)[c4], bb = ((const float4*)b1)[c4];
    float vx = fmaxf((a.x + b.x + c.x + d.x) * s.x + bb.x, 0.f);
    float vy = fmaxf((a.y + b.y + c.y + d.y) * s.y + bb.y, 0.f);
    float vz = fmaxf((a.z + b.z + c.z + d.z) * s.z + bb.z, 0.f);
    float vw = fmaxf((a.w + b.w + c.w + d.w) * s.w + bb.w, 0.f);
    int2 o; o.x = pkbf(vx, vy); o.y = pkbf(vz, vw);
    ((int2*)y)[id] = o;
}

// ---------------------------------------------------------------------------
// K2: fused fai/sit/gama projections. (unchanged)
// nt<4 -> P bf16 [8192,256] (cols 0-127 fai, 128-255 sit);
// nt>=4 -> G bf16 [8,128,1024] (transposed, AV GEMM B-operand).
// ---------------------------------------------------------------------------
__global__ __launch_bounds__(256, 2) void k_proj3(
    const unsigned short* __restrict__ y,
    const float* __restrict__ w_fai, const float* __restrict__ w_sit,
    const float* __restrict__ w_gama,
    const float* __restrict__ fs, const float* __restrict__ fb,
    const float* __restrict__ ss, const float* __restrict__ sb,
    const float* __restrict__ gs, const float* __restrict__ gb,
    unsigned short* __restrict__ P, unsigned short* __restrict__ G)
{
    __shared__ unsigned short At[64 * 40];
    __shared__ unsigned short Bt[64 * 40];
    const int tid = threadIdx.x;
    const int nt = blockIdx.x, mt = blockIdx.y;
    const int m0 = mt * 64;
    const float *W, *S, *Bb;
    if (nt < 2)      { W = w_fai;  S = fs; Bb = fb; }
    else if (nt < 4) { W = w_sit;  S = ss; Bb = sb; }
    else             { W = w_gama; S = gs; Bb = gb; }
    const int roff = (nt * 64) & 127;
    const int lane = tid & 63, wid = tid >> 6;
    const int wm = wid & 1, wn = wid >> 1;
    const int quad = lane >> 4, r16 = lane & 15;
    float4_t acc[2][2] = {};

    for (int k0 = 0; k0 < 256; k0 += 32) {
        {   // A: y tile 64x32 bf16, direct copy
            const int row = tid >> 2, pp = tid & 3;
            *(int4*)&At[row * 40 + pp * 8] =
                *(const int4*)(y + (m0 + row) * 256 + k0 + pp * 8);
        }
        #pragma unroll
        for (int l = 0; l < 2; ++l) {   // B: W tile 64x32 fp32 -> bf16
            const int slot = l * 256 + tid;
            const int row = slot >> 3, pp = slot & 7;
            float4 v = *(const float4*)(W + (roff + row) * 256 + k0 + pp * 4);
            int2 wv; wv.x = pkbf(v.x, v.y); wv.y = pkbf(v.z, v.w);
            *(int2*)&Bt[row * 40 + pp * 4] = wv;
        }
        __syncthreads();
        short8_t aF[2], bF[2];
        #pragma unroll
        for (int i = 0; i < 2; ++i)
            aF[i] = *(const short8_t*)&At[(wm * 32 + i * 16 + r16) * 40 + quad * 8];
        #pragma unroll
        for (int j = 0; j < 2; ++j)
            bF[j] = *(const short8_t*)&Bt[(wn * 32 + j * 16 + r16) * 40 + quad * 8];
        #pragma unroll
        for (int i = 0; i < 2; ++i)
            #pragma unroll
            for (int j = 0; j < 2; ++j)
                acc[i][j] = __builtin_amdgcn_mfma_f32_16x16x32_bf16(aF[i], bF[j], acc[i][j], 0, 0, 0);
        __syncthreads();
    }
    #pragma unroll
    for (int i = 0; i < 2; ++i) {
        const int mg = m0 + wm * 32 + i * 16 + quad * 4;
        #pragma unroll
        for (int j = 0; j < 2; ++j) {
            const int nl = wn * 32 + j * 16 + r16;
            const float sc = S[roff + nl], bc = Bb[roff + nl];
            if (nt < 4) {
                const int col = nt * 64 + nl;
                #pragma unroll
                for (int r = 0; r < 4; ++r) {
                    float v = fmaxf(acc[i][j][r] * sc + bc, 0.f);
                    P[(mg + r) * 256 + col] = f2bf(v);
                }
            } else {
                const int c = roff + nl;
                #pragma unroll
                for (int r = 0; r < 4; ++r) {
                    float v = fmaxf(acc[i][j][r] * sc + bc, 0.f);
                    const int sp = mg + r;
                    G[((sp >> 10) * 128 + c) * 1024 + (sp & 1023)] = f2bf(v);
                }
            }
        }
    }
}

// ---------------------------------------------------------------------------
// K3+K4 fused: k_attn with async-STAGE split + lgkm-only barriers.
// launch_bounds(256,1): LDS (77.7 KB) already caps at 2 blocks/CU, so the
// relaxed VGPR bound (<=256) costs no occupancy and removes the r3 spill.
// G-tile loads issued before GEMM1 (committed after its barrier); sit(ms=1)
// loads issued before GEMM2 — they stay in flight across the raw barriers.
// Grid (16 nt, 32 = b*4+kc). Partials Opart[kc][8][1024][128] fp32.
// ---------------------------------------------------------------------------
#define LSTR 152
__global__ __launch_bounds__(256, 1) void k_attn(
    const unsigned short* __restrict__ P, const unsigned short* __restrict__ G,
    float* __restrict__ Opart)
{
    __shared__ unsigned short At[64 * LSTR];    // fai tile [64 n][128 c]
    __shared__ unsigned short Bt[128 * LSTR];   // sit tile, then G tile
    __shared__ unsigned short Sl[64 * LSTR];    // sigma(S) [64 n][128 m]
    const int tid = threadIdx.x;
    const int nt = blockIdx.x, zz = blockIdx.y;
    const int b = zz >> 2, kc = zz & 3;
    const int n0 = nt * 64;
    const int base = b * 1024;
    const int lane = tid & 63, wid = tid >> 6;
    const int wm = wid & 1, wn = wid >> 1;
    const int quad = lane >> 4, r16 = lane & 15;
    const int srow = tid >> 4, sp16 = tid & 15;     // staging row/seg (16B units)
    float4_t acc2[2][4] = {};
    int4 rs[8], rg[8];

    // stage fai tile (direct), issue sit(ms=0) loads into rs
    #pragma unroll
    for (int l = 0; l < 4; ++l) {
        const int slot = l * 256 + tid;
        const int row = slot >> 4, p = slot & 15;
        *(int4*)&At[row * LSTR + p * 8] =
            *(const int4*)(P + (base + n0 + row) * 256 + p * 8);
    }
    {
        const int m1 = kc * 256;
        #pragma unroll
        for (int l = 0; l < 8; ++l)
            rs[l] = *(const int4*)(P + (base + m1 + (l * 16 + srow)) * 256 + 128 + sp16 * 8);
    }
    #pragma unroll
    for (int ms = 0; ms < 2; ++ms) {
        const int m1 = kc * 256 + ms * 128;
        // commit sit tile [128 m][128 c] from regs
        #pragma unroll
        for (int l = 0; l < 8; ++l)
            *(int4*)&Bt[(l * 16 + srow) * LSTR + sp16 * 8] = rs[l];
        BARRIER_LGKM();   // At + Bt(sit) visible
        // issue G(ms) loads -> rg (consumed after GEMM1's barrier)
        #pragma unroll
        for (int l = 0; l < 8; ++l)
            rg[l] = *(const int4*)(G + (b * 128 + (l * 16 + srow)) * 1024 + m1 + sp16 * 8);
        // GEMM1: S[n,m], wave tile 32(n) x 64(m)
        float4_t acc1[2][4] = {};
        #pragma unroll
        for (int c = 0; c < 4; ++c) {
            short8_t aF[2], bF[4];
            #pragma unroll
            for (int i = 0; i < 2; ++i)
                aF[i] = *(const short8_t*)&At[(wm * 32 + i * 16 + r16) * LSTR + c * 32 + quad * 8];
            #pragma unroll
            for (int j = 0; j < 4; ++j)
                bF[j] = *(const short8_t*)&Bt[(wn * 64 + j * 16 + r16) * LSTR + c * 32 + quad * 8];
            #pragma unroll
            for (int i = 0; i < 2; ++i)
                #pragma unroll
                for (int j = 0; j < 4; ++j)
                    acc1[i][j] = __builtin_amdgcn_mfma_f32_16x16x32_bf16(aF[i], bF[j], acc1[i][j], 0, 0, 0);
        }
        BARRIER_LGKM();   // everyone's Bt(sit) reads done
        // sigmoid -> Sl (LDS only)
        #pragma unroll
        for (int i = 0; i < 2; ++i) {
            const int nl = wm * 32 + i * 16 + quad * 4;
            #pragma unroll
            for (int j = 0; j < 4; ++j) {
                const int ml = wn * 64 + j * 16 + r16;
                #pragma unroll
                for (int r = 0; r < 4; ++r) {
                    const float xv = acc1[i][j][r];
                    const float e = __expf(-xv);
                    const float v = __builtin_amdgcn_rcpf(1.0f + e);
                    Sl[(nl + r) * LSTR + ml] = f2bf(v);
                }
            }
        }
        // commit G tile [128 ch][128 m] from regs
        #pragma unroll
        for (int l = 0; l < 8; ++l)
            *(int4*)&Bt[(l * 16 + srow) * LSTR + sp16 * 8] = rg[l];
        // issue sit(ms=1) loads (consumed next iteration, after GEMM2)
        if (ms == 0) {
            const int m1n = kc * 256 + 128;
            #pragma unroll
            for (int l = 0; l < 8; ++l)
                rs[l] = *(const int4*)(P + (base + m1n + (l * 16 + srow)) * 256 + 128 + sp16 * 8);
        }
        BARRIER_LGKM();   // Sl + Bt(G) visible
        // GEMM2: O[n,ch] += Sl . G^T, wave tile 32(n) x 64(ch)
        #pragma unroll
        for (int c = 0; c < 4; ++c) {
            short8_t aF[2], bF[4];
            #pragma unroll
            for (int i = 0; i < 2; ++i)
                aF[i] = *(const short8_t*)&Sl[(wm * 32 + i * 16 + r16) * LSTR + c * 32 + quad * 8];
            #pragma unroll
            for (int j = 0; j < 4; ++j)
                bF[j] = *(const short8_t*)&Bt[(wn * 64 + j * 16 + r16) * LSTR + c * 32 + quad * 8];
            #pragma unroll
            for (int i = 0; i < 2; ++i)
                #pragma unroll
                for (int j = 0; j < 4; ++j)
                    acc2[i][j] = __builtin_amdgcn_mfma_f32_16x16x32_bf16(aF[i], bF[j], acc2[i][j], 0, 0, 0);
        }
        BARRIER_LGKM();   // before next ms overwrites Bt / Sl
    }
    float* op = Opart + (size_t)kc * 1048576 + (size_t)b * 131072;
    #pragma unroll
    for (int i = 0; i < 2; ++i) {
        const int nl = n0 + wm * 32 + i * 16 + quad * 4;
        #pragma unroll
        for (int j = 0; j < 4; ++j) {
            const int ch = wn * 64 + j * 16 + r16;
            #pragma unroll
            for (int r = 0; r < 4; ++r)
                op[(nl + r) * 128 + ch] = acc2[i][j][r];
        }
    }
}

// ---------------------------------------------------------------------------
// K5: sum 4 O-partials + bilinear x8 upsample (align_corners). (unchanged)
// ---------------------------------------------------------------------------
__global__ __launch_bounds__(256, 2) void k_up(
    const float* __restrict__ Opart, float* __restrict__ out)
{
    __shared__ float l0[32 * 136];
    __shared__ float l1[32 * 136];
    const int tid = threadIdx.x;
    const int yb = blockIdx.x, b = blockIdx.y;
    const float sc = 31.0f / 255.0f;
    const float fy = yb * sc;
    const int y0 = (int)fy;
    const float wy = fy - (float)y0;
    const int y1 = (y0 + 1 < 32) ? y0 + 1 : 31;
    const float4* r0 = (const float4*)(Opart + (size_t)b * 131072 + y0 * 4096);
    const float4* r1 = (const float4*)(Opart + (size_t)b * 131072 + y1 * 4096);
    #pragma unroll
    for (int j = 0; j < 4; ++j) {
        const int id = j * 256 + tid;       // 0..1023 float4 chunks of a row
        const int xs = id >> 5, c4 = id & 31;
        float4 a0 = r0[id], a1 = r1[id];
        #pragma unroll
        for (int kc = 1; kc < 4; ++kc) {
            float4 t0 = r0[id + kc * 262144], t1 = r1[id + kc * 262144];
            a0.x += t0.x; a0.y += t0.y; a0.z += t0.z; a0.w += t0.w;
            a1.x += t1.x; a1.y += t1.y; a1.z += t1.z; a1.w += t1.w;
        }
        *(float4*)(l0 + xs * 136 + c4 * 4) = a0;
        *(float4*)(l1 + xs * 136 + c4 * 4) = a1;
    }
    __syncthreads();
    const float fx = tid * sc;
    const int x0 = (int)fx;
    const float wx = fx - (float)x0;
    const int x1 = (x0 + 1 < 32) ? x0 + 1 : 31;
    const float w00 = (1.f - wy) * (1.f - wx), w01 = (1.f - wy) * wx;
    const float w10 = wy * (1.f - wx), w11 = wy * wx;
    const float* a = l0 + x0 * 136;
    const float* bq = l0 + x1 * 136;
    const float* c = l1 + x0 * 136;
    const float* d = l1 + x1 * 136;
    float* op = out + (size_t)b * 8388608 + yb * 256 + tid;
    #pragma unroll 4
    for (int ch = 0; ch < 128; ++ch)
        op[ch * 65536] = w00 * a[ch] + w01 * bq[ch] + w10 * c[ch] + w11 * d[ch];
}

extern "C" void kernel_launch(void* const* d_in, const int* in_sizes, int n_in,
                              void* d_out, int out_size, void* d_ws, size_t ws_size,
                              hipStream_t stream) {
    (void)in_sizes; (void)n_in; (void)out_size; (void)ws_size;
    const float* x      = (const float*)d_in[0];
    const float* w1     = (const float*)d_in[1];
    const float* bn1_s  = (const float*)d_in[2];
    const float* bn1_b  = (const float*)d_in[3];
    const float* w_fai  = (const float*)d_in[4];
    const float* bnf_s  = (const float*)d_in[5];
    const float* bnf_b  = (const float*)d_in[6];
    const float* w_sit  = (const float*)d_in[7];
    const float* bns_s  = (const float*)d_in[8];
    const float* bns_b  = (const float*)d_in[9];
    const float* w_gama = (const float*)d_in[10];
    const float* bng_s  = (const float*)d_in[11];
    const float* bng_b  = (const float*)d_in[12];
    float* out = (float*)d_out;

    char* ws = (char*)d_ws;
    // [0,32MB): conv partials pc; after k_reduce the region is reused:
    //   Opart @ 16MB (16 MB, k_attn partials)
    float*          pc    = (float*)ws;                                 // [4][8192][256]
    float*          Opart = (float*)(ws + 16u * 1024 * 1024);           // [4][8][1024][128]
    unsigned short* y     = (unsigned short*)(ws + 32u * 1024 * 1024);  // 4 MB
    unsigned short* P     = (unsigned short*)(ws + 36u * 1024 * 1024);  // 4 MB
    unsigned short* G     = (unsigned short*)(ws + 40u * 1024 * 1024);  // 2 MB
    unsigned short* w1s   = (unsigned short*)(ws + 44u * 1024 * 1024);  // 2 MB

    k_wprep <<<dim3(512),      256, 0, stream>>>(w1, w1s);
    k_conv1 <<<dim3(64, 4),    512, 0, stream>>>(x, w1s, pc);
    k_reduce<<<dim3(2048),     256, 0, stream>>>(pc, bn1_s, bn1_b, y);
    k_proj3 <<<dim3(6, 128),   256, 0, stream>>>(y, w_fai, w_sit, w_gama,
                                                 bnf_s, bnf_b, bns_s, bns_b,
                                                 bng_s, bng_b, P, G);
    k_attn  <<<dim3(16, 32),   256, 0, stream>>>(P, G, Opart);
    k_up    <<<dim3(256, 8),   256, 0, stream>>>(Opart, out);
}

// Round 6
// 481.368 us; speedup vs baseline: 1.0586x; 1.0317x over previous
//
#include <hip/hip_runtime.h>

typedef __attribute__((ext_vector_type(8))) short short8_t;
typedef __attribute__((ext_vector_type(4))) float float4_t;

__device__ __forceinline__ unsigned short f2bf(float f) {
    unsigned int u = __float_as_uint(f);
    return (unsigned short)((u + 0x7FFFu + ((u >> 16) & 1u)) >> 16);
}
__device__ __forceinline__ unsigned int pkbf(float a, float b) {
    return (unsigned int)f2bf(a) | ((unsigned int)f2bf(b) << 16);
}

// Barrier that does NOT drain vmcnt: LDS ordering fully protected
// (lgkmcnt(0) before s_barrier) but global loads into registers stay in
// flight across the barrier (validated correct in round 5's passing run).
#define BARRIER_LGKM() asm volatile("s_waitcnt lgkmcnt(0)\ns_barrier" ::: "memory")

// ---------------------------------------------------------------------------
// K0: one-shot w1 fp32 -> bf16 ([256][4096] row-major).
// ---------------------------------------------------------------------------
__global__ __launch_bounds__(256) void k_wprep(
    const float* __restrict__ w1, unsigned short* __restrict__ w1s)
{
    const int id = blockIdx.x * 256 + threadIdx.x;   // 131072, 8 floats each
    const float4* s = (const float4*)(w1 + id * 8);
    float4 a = s[0], b = s[1];
    int4 o;
    o.x = pkbf(a.x, a.y); o.y = pkbf(a.z, a.w);
    o.z = pkbf(b.x, b.y); o.w = pkbf(b.z, b.w);
    *(int4*)(w1s + id * 8) = o;
}

// ---------------------------------------------------------------------------
// K1: conv1 implicit GEMM, 512-thread structure (128M x 256N, BK=32,
// split-K x4, 8 waves 2m x 4n). CHANGE vs r2 (474us best): double-buffered
// LDS + ONE lgkm-only barrier per iteration (was 2 __syncthreads). Depth-2
// register sets: loads for tile t+2 are issued at iter t and consumed at the
// COMMIT at end of iter t+1 (~1 full iter of latency coverage), surviving
// the intervening barrier. Commits write the buffer MFMA is not reading.
// Grid 256 = 1 block/CU, so launch_bounds(512,1) costs no occupancy.
// A-LDS XOR swizzle on k-slot, matching fragment read (unchanged).
// ---------------------------------------------------------------------------
#define CONV_LOAD_A(dst, k0q) {                                               \
    const int ic = (k0q) >> 6, kh0 = ((k0q) >> 3) & 7;                        \
    const int xr = (oh0 + ohl) * 8 + kh0 + khl;                               \
    const float4* s4 = (const float4*)(x + (((bi * 64 + ic) * 256 + xr) * 256 + segA * 16)); \
    dst[0] = s4[0]; dst[1] = s4[1]; dst[2] = s4[2]; dst[3] = s4[3];           \
}
#define CONV_LOAD_B(dst, k0q) {                                               \
    _Pragma("unroll")                                                         \
    for (int l = 0; l < 4; ++l) {                                             \
        const int slot = l * 256 + tA;                                        \
        const int row = slot >> 2, p = slot & 3;                              \
        dst[l] = *(const int4*)(w1s + row * 4096 + (k0q) + p * 8);            \
    }                                                                         \
}
#define CONV_COMMIT_A(Abuf, src) {                                            \
    int4 p0, p1;                                                              \
    p0.x = pkbf(src[0].x, src[0].y); p0.y = pkbf(src[0].z, src[0].w);         \
    p0.z = pkbf(src[1].x, src[1].y); p0.w = pkbf(src[1].z, src[1].w);         \
    p1.x = pkbf(src[2].x, src[2].y); p1.y = pkbf(src[2].z, src[2].w);         \
    p1.z = pkbf(src[3].x, src[3].y); p1.w = pkbf(src[3].z, src[3].w);         \
    *(int4*)&(Abuf)[rowA * 40 + koffA] = p0;                                  \
    *(int4*)&(Abuf)[(rowA + 1) * 40 + koffA] = p1;                            \
}
#define CONV_COMMIT_B(Bbuf, src) {                                            \
    _Pragma("unroll")                                                         \
    for (int l = 0; l < 4; ++l) {                                             \
        const int slot = l * 256 + tA;                                        \
        const int row = slot >> 2, p = slot & 3;                              \
        *(int4*)&(Bbuf)[row * 40 + p * 8] = src[l];                           \
    }                                                                         \
}
#define CONV_MFMA(Abuf, Bbuf) {                                               \
    short8_t aF[4], bF[4];                                                    \
    _Pragma("unroll")                                                         \
    for (int i = 0; i < 4; ++i) {                                             \
        const int R = wm * 64 + i * 16 + r16;                                 \
        aF[i] = *(const short8_t*)&(Abuf)[R * 40 + (quad ^ ((r16 >> 1) & 3)) * 8]; \
    }                                                                         \
    _Pragma("unroll")                                                         \
    for (int j = 0; j < 4; ++j)                                               \
        bF[j] = *(const short8_t*)&(Bbuf)[(wn * 64 + j * 16 + r16) * 40 + quad * 8]; \
    _Pragma("unroll")                                                         \
    for (int i = 0; i < 4; ++i)                                               \
        _Pragma("unroll")                                                     \
        for (int j = 0; j < 4; ++j)                                           \
            acc[i][j] = __builtin_amdgcn_mfma_f32_16x16x32_bf16(aF[i], bF[j], acc[i][j], 0, 0, 0); \
}

__global__ __launch_bounds__(512, 1) void k_conv1(
    const float* __restrict__ x, const unsigned short* __restrict__ w1s,
    float* __restrict__ part)
{
    __shared__ unsigned short At[2][128 * 40];   // 2 x 10 KB
    __shared__ unsigned short Bt[2][256 * 40];   // 2 x 20 KB
    const int tid = threadIdx.x;
    const int mt = blockIdx.x, kc = blockIdx.y;
    const int m0 = mt * 128;
    const int bi = mt >> 3;
    const int oh0 = (mt & 7) * 4;
    const int lane = tid & 63, wid = tid >> 6;
    const int wm = wid & 1, wn = wid >> 1;          // 2 x 4 waves
    const int quad = lane >> 4, r16 = lane & 15;
    const bool isA = tid < 256;
    const int tA = tid & 255;
    const int rA = tA >> 4, segA = tA & 15;
    const int ohl = rA >> 2, khl = rA & 3;
    const int rowA = ohl * 32 + segA * 2;
    const int koffA = (khl ^ (segA & 3)) * 8;       // swizzled k-slot (shorts)
    const int kbase = kc * 1024;
    float4_t acc[4][4] = {};
    float4 sA0[4], sA1[4];   // A reg sets: tile t -> set (t&1)
    int4 sB0[4], sB1[4];     // B reg sets

    // prologue: load tiles 0,1; commit tile 0 -> buf0
    if (isA) { CONV_LOAD_A(sA0, kbase); CONV_LOAD_A(sA1, kbase + 32); }
    else     { CONV_LOAD_B(sB0, kbase); CONV_LOAD_B(sB1, kbase + 32); }
    if (isA) CONV_COMMIT_A(At[0], sA0) else CONV_COMMIT_B(Bt[0], sB0);
    BARRIER_LGKM();   // buf0 visible; tile-1 loads remain in flight

    for (int it = 0; it < 32; ++it) {
        const int cur = it & 1;
        // compute on current buffer
        CONV_MFMA(At[cur], Bt[cur]);
        // commit tile it+1 into the other buffer (loads issued >=1 iter ago)
        if (it + 1 < 32) {
            if (isA) {
                if ((it + 1) & 1) CONV_COMMIT_A(At[1], sA1)
                else              CONV_COMMIT_A(At[0], sA0)
            } else {
                if ((it + 1) & 1) CONV_COMMIT_B(Bt[1], sB1)
                else              CONV_COMMIT_B(Bt[0], sB0)
            }
        }
        // issue loads for tile it+2 into the set just freed (set it&1)
        if (it + 2 < 32) {
            const int k0 = kbase + (it + 2) * 32;
            if (isA) {
                if (cur) CONV_LOAD_A(sA1, k0) else CONV_LOAD_A(sA0, k0);
            } else {
                if (cur) CONV_LOAD_B(sB1, k0) else CONV_LOAD_B(sB0, k0);
            }
        }
        BARRIER_LGKM();   // single barrier per iteration
    }
    float* pp = part + ((size_t)kc << 21);
    #pragma unroll
    for (int i = 0; i < 4; ++i) {
        const int mg = m0 + wm * 64 + i * 16 + quad * 4;
        #pragma unroll
        for (int j = 0; j < 4; ++j) {
            const int ng = wn * 64 + j * 16 + r16;
            #pragma unroll
            for (int r = 0; r < 4; ++r)
                pp[(mg + r) * 256 + ng] = acc[i][j][r];
        }
    }
}

// ---------------------------------------------------------------------------
// K1b: reduce 4 split-K partials + BN + ReLU -> y bf16 [8192,256]. (unchanged)
// ---------------------------------------------------------------------------
__global__ __launch_bounds__(256, 4) void k_reduce(
    const float* __restrict__ part, const float* __restrict__ s1,
    const float* __restrict__ b1, unsigned short* __restrict__ y)
{
    const int id = blockIdx.x * 256 + threadIdx.x;   // 0..524287 float4 slots
    const int c4 = id & 63;
    const float4* p = (const float4*)part + id;
    float4 a = p[0], b = p[524288], c = p[1048576], d = p[1572864];
    float4 s = ((const float4*)s1)[c4], bb = ((const float4*)b1)[c4];
    float vx = fmaxf((a.x + b.x + c.x + d.x) * s.x + bb.x, 0.f);
    float vy = fmaxf((a.y + b.y + c.y + d.y) * s.y + bb.y, 0.f);
    float vz = fmaxf((a.z + b.z + c.z + d.z) * s.z + bb.z, 0.f);
    float vw = fmaxf((a.w + b.w + c.w + d.w) * s.w + bb.w, 0.f);
    int2 o; o.x = pkbf(vx, vy); o.y = pkbf(vz, vw);
    ((int2*)y)[id] = o;
}

// ---------------------------------------------------------------------------
// K2: fused fai/sit/gama projections. (unchanged, r2-exact)
// nt<4 -> P bf16 [8192,256] (cols 0-127 fai, 128-255 sit);
// nt>=4 -> G bf16 [8,128,1024] (transposed, AV GEMM B-operand).
// ---------------------------------------------------------------------------
__global__ __launch_bounds__(256, 2) void k_proj3(
    const unsigned short* __restrict__ y,
    const float* __restrict__ w_fai, const float* __restrict__ w_sit,
    const float* __restrict__ w_gama,
    const float* __restrict__ fs, const float* __restrict__ fb,
    const float* __restrict__ ss, const float* __restrict__ sb,
    const float* __restrict__ gs, const float* __restrict__ gb,
    unsigned short* __restrict__ P, unsigned short* __restrict__ G)
{
    __shared__ unsigned short At[64 * 40];
    __shared__ unsigned short Bt[64 * 40];
    const int tid = threadIdx.x;
    const int nt = blockIdx.x, mt = blockIdx.y;
    const int m0 = mt * 64;
    const float *W, *S, *Bb;
    if (nt < 2)      { W = w_fai;  S = fs; Bb = fb; }
    else if (nt < 4) { W = w_sit;  S = ss; Bb = sb; }
    else             { W = w_gama; S = gs; Bb = gb; }
    const int roff = (nt * 64) & 127;
    const int lane = tid & 63, wid = tid >> 6;
    const int wm = wid & 1, wn = wid >> 1;
    const int quad = lane >> 4, r16 = lane & 15;
    float4_t acc[2][2] = {};

    for (int k0 = 0; k0 < 256; k0 += 32) {
        {   // A: y tile 64x32 bf16, direct copy
            const int row = tid >> 2, pp = tid & 3;
            *(int4*)&At[row * 40 + pp * 8] =
                *(const int4*)(y + (m0 + row) * 256 + k0 + pp * 8);
        }
        #pragma unroll
        for (int l = 0; l < 2; ++l) {   // B: W tile 64x32 fp32 -> bf16
            const int slot = l * 256 + tid;
            const int row = slot >> 3, pp = slot & 7;
            float4 v = *(const float4*)(W + (roff + row) * 256 + k0 + pp * 4);
            int2 wv; wv.x = pkbf(v.x, v.y); wv.y = pkbf(v.z, v.w);
            *(int2*)&Bt[row * 40 + pp * 4] = wv;
        }
        __syncthreads();
        short8_t aF[2], bF[2];
        #pragma unroll
        for (int i = 0; i < 2; ++i)
            aF[i] = *(const short8_t*)&At[(wm * 32 + i * 16 + r16) * 40 + quad * 8];
        #pragma unroll
        for (int j = 0; j < 2; ++j)
            bF[j] = *(const short8_t*)&Bt[(wn * 32 + j * 16 + r16) * 40 + quad * 8];
        #pragma unroll
        for (int i = 0; i < 2; ++i)
            #pragma unroll
            for (int j = 0; j < 2; ++j)
                acc[i][j] = __builtin_amdgcn_mfma_f32_16x16x32_bf16(aF[i], bF[j], acc[i][j], 0, 0, 0);
        __syncthreads();
    }
    #pragma unroll
    for (int i = 0; i < 2; ++i) {
        const int mg = m0 + wm * 32 + i * 16 + quad * 4;
        #pragma unroll
        for (int j = 0; j < 2; ++j) {
            const int nl = wn * 32 + j * 16 + r16;
            const float sc = S[roff + nl], bc = Bb[roff + nl];
            if (nt < 4) {
                const int col = nt * 64 + nl;
                #pragma unroll
                for (int r = 0; r < 4; ++r) {
                    float v = fmaxf(acc[i][j][r] * sc + bc, 0.f);
                    P[(mg + r) * 256 + col] = f2bf(v);
                }
            } else {
                const int c = roff + nl;
                #pragma unroll
                for (int r = 0; r < 4; ++r) {
                    float v = fmaxf(acc[i][j][r] * sc + bc, 0.f);
                    const int sp = mg + r;
                    G[((sp >> 10) * 128 + c) * 1024 + (sp & 1023)] = f2bf(v);
                }
            }
        }
    }
}

// ---------------------------------------------------------------------------
// K3+K4 fused: k_attn — r2-exact (474us version). Per block: 64 n-rows x
// 128 ch, m-range kc*256..+256 (2 subtiles). GEMM1 S = fai^T sit; sigmoid in
// registers; S through LDS only; GEMM2 Opart += sigma(S).G^T.
// Grid (16 nt, 32 = b*4+kc). Partials Opart[kc][8][1024][128] fp32.
// ---------------------------------------------------------------------------
#define LSTR 152
__global__ __launch_bounds__(256, 2) void k_attn(
    const unsigned short* __restrict__ P, const unsigned short* __restrict__ G,
    float* __restrict__ Opart)
{
    __shared__ unsigned short At[64 * LSTR];    // fai tile [64 n][128 c]
    __shared__ unsigned short Bt[128 * LSTR];   // sit tile, then G tile
    __shared__ unsigned short Sl[64 * LSTR];    // sigma(S) [64 n][128 m]
    const int tid = threadIdx.x;
    const int nt = blockIdx.x, zz = blockIdx.y;
    const int b = zz >> 2, kc = zz & 3;
    const int n0 = nt * 64;
    const int base = b * 1024;
    const int lane = tid & 63, wid = tid >> 6;
    const int wm = wid & 1, wn = wid >> 1;
    const int quad = lane >> 4, r16 = lane & 15;
    float4_t acc2[2][4] = {};

    // stage fai tile once (reused by both m-subtiles)
    #pragma unroll
    for (int l = 0; l < 4; ++l) {
        const int slot = l * 256 + tid;
        const int row = slot >> 4, p = slot & 15;
        *(int4*)&At[row * LSTR + p * 8] =
            *(const int4*)(P + (base + n0 + row) * 256 + p * 8);
    }
    for (int ms = 0; ms < 2; ++ms) {
        const int m1 = kc * 256 + ms * 128;
        // stage sit tile [128 m][128 c]
        #pragma unroll
        for (int l = 0; l < 8; ++l) {
            const int slot = l * 256 + tid;
            const int row = slot >> 4, p = slot & 15;
            *(int4*)&Bt[row * LSTR + p * 8] =
                *(const int4*)(P + (base + m1 + row) * 256 + 128 + p * 8);
        }
        __syncthreads();
        // GEMM1: S[n,m], wave tile 32(n) x 64(m)
        float4_t acc1[2][4] = {};
        #pragma unroll
        for (int c = 0; c < 4; ++c) {
            short8_t aF[2], bF[4];
            #pragma unroll
            for (int i = 0; i < 2; ++i)
                aF[i] = *(const short8_t*)&At[(wm * 32 + i * 16 + r16) * LSTR + c * 32 + quad * 8];
            #pragma unroll
            for (int j = 0; j < 4; ++j)
                bF[j] = *(const short8_t*)&Bt[(wn * 64 + j * 16 + r16) * LSTR + c * 32 + quad * 8];
            #pragma unroll
            for (int i = 0; i < 2; ++i)
                #pragma unroll
                for (int j = 0; j < 4; ++j)
                    acc1[i][j] = __builtin_amdgcn_mfma_f32_16x16x32_bf16(aF[i], bF[j], acc1[i][j], 0, 0, 0);
        }
        __syncthreads();   // Bt(sit) reads done; prev-ms Sl reads long done
        // sigmoid -> Sl (LDS only)
        #pragma unroll
        for (int i = 0; i < 2; ++i) {
            const int nl = wm * 32 + i * 16 + quad * 4;
            #pragma unroll
            for (int j = 0; j < 4; ++j) {
                const int ml = wn * 64 + j * 16 + r16;
                #pragma unroll
                for (int r = 0; r < 4; ++r) {
                    const float xv = acc1[i][j][r];
                    const float e = __expf(-xv);
                    const float v = __builtin_amdgcn_rcpf(1.0f + e);
                    Sl[(nl + r) * LSTR + ml] = f2bf(v);
                }
            }
        }
        // restage Bt with G tile [128 ch][128 m]
        #pragma unroll
        for (int l = 0; l < 8; ++l) {
            const int slot = l * 256 + tid;
            const int row = slot >> 4, p = slot & 15;
            *(int4*)&Bt[row * LSTR + p * 8] =
                *(const int4*)(G + (b * 128 + row) * 1024 + m1 + p * 8);
        }
        __syncthreads();   // Sl + G visible
        // GEMM2: O[n,ch] += Sl . G^T, wave tile 32(n) x 64(ch)
        #pragma unroll
        for (int c = 0; c < 4; ++c) {
            short8_t aF[2], bF[4];
            #pragma unroll
            for (int i = 0; i < 2; ++i)
                aF[i] = *(const short8_t*)&Sl[(wm * 32 + i * 16 + r16) * LSTR + c * 32 + quad * 8];
            #pragma unroll
            for (int j = 0; j < 4; ++j)
                bF[j] = *(const short8_t*)&Bt[(wn * 64 + j * 16 + r16) * LSTR + c * 32 + quad * 8];
            #pragma unroll
            for (int i = 0; i < 2; ++i)
                #pragma unroll
                for (int j = 0; j < 4; ++j)
                    acc2[i][j] = __builtin_amdgcn_mfma_f32_16x16x32_bf16(aF[i], bF[j], acc2[i][j], 0, 0, 0);
        }
        __syncthreads();   // before next ms overwrites Bt / Sl
    }
    float* op = Opart + (size_t)kc * 1048576 + (size_t)b * 131072;
    #pragma unroll
    for (int i = 0; i < 2; ++i) {
        const int nl = n0 + wm * 32 + i * 16 + quad * 4;
        #pragma unroll
        for (int j = 0; j < 4; ++j) {
            const int ch = wn * 64 + j * 16 + r16;
            #pragma unroll
            for (int r = 0; r < 4; ++r)
                op[(nl + r) * 128 + ch] = acc2[i][j][r];
        }
    }
}

// ---------------------------------------------------------------------------
// K5: sum 4 O-partials + bilinear x8 upsample (align_corners). (unchanged)
// ---------------------------------------------------------------------------
__global__ __launch_bounds__(256, 2) void k_up(
    const float* __restrict__ Opart, float* __restrict__ out)
{
    __shared__ float l0[32 * 136];
    __shared__ float l1[32 * 136];
    const int tid = threadIdx.x;
    const int yb = blockIdx.x, b = blockIdx.y;
    const float sc = 31.0f / 255.0f;
    const float fy = yb * sc;
    const int y0 = (int)fy;
    const float wy = fy - (float)y0;
    const int y1 = (y0 + 1 < 32) ? y0 + 1 : 31;
    const float4* r0 = (const float4*)(Opart + (size_t)b * 131072 + y0 * 4096);
    const float4* r1 = (const float4*)(Opart + (size_t)b * 131072 + y1 * 4096);
    #pragma unroll
    for (int j = 0; j < 4; ++j) {
        const int id = j * 256 + tid;       // 0..1023 float4 chunks of a row
        const int xs = id >> 5, c4 = id & 31;
        float4 a0 = r0[id], a1 = r1[id];
        #pragma unroll
        for (int kc = 1; kc < 4; ++kc) {
            float4 t0 = r0[id + kc * 262144], t1 = r1[id + kc * 262144];
            a0.x += t0.x; a0.y += t0.y; a0.z += t0.z; a0.w += t0.w;
            a1.x += t1.x; a1.y += t1.y; a1.z += t1.z; a1.w += t1.w;
        }
        *(float4*)(l0 + xs * 136 + c4 * 4) = a0;
        *(float4*)(l1 + xs * 136 + c4 * 4) = a1;
    }
    __syncthreads();
    const float fx = tid * sc;
    const int x0 = (int)fx;
    const float wx = fx - (float)x0;
    const int x1 = (x0 + 1 < 32) ? x0 + 1 : 31;
    const float w00 = (1.f - wy) * (1.f - wx), w01 = (1.f - wy) * wx;
    const float w10 = wy * (1.f - wx), w11 = wy * wx;
    const float* a = l0 + x0 * 136;
    const float* bq = l0 + x1 * 136;
    const float* c = l1 + x0 * 136;
    const float* d = l1 + x1 * 136;
    float* op = out + (size_t)b * 8388608 + yb * 256 + tid;
    #pragma unroll 4
    for (int ch = 0; ch < 128; ++ch)
        op[ch * 65536] = w00 * a[ch] + w01 * bq[ch] + w10 * c[ch] + w11 * d[ch];
}

extern "C" void kernel_launch(void* const* d_in, const int* in_sizes, int n_in,
                              void* d_out, int out_size, void* d_ws, size_t ws_size,
                              hipStream_t stream) {
    (void)in_sizes; (void)n_in; (void)out_size; (void)ws_size;
    const float* x      = (const float*)d_in[0];
    const float* w1     = (const float*)d_in[1];
    const float* bn1_s  = (const float*)d_in[2];
    const float* bn1_b  = (const float*)d_in[3];
    const float* w_fai  = (const float*)d_in[4];
    const float* bnf_s  = (const float*)d_in[5];
    const float* bnf_b  = (const float*)d_in[6];
    const float* w_sit  = (const float*)d_in[7];
    const float* bns_s  = (const float*)d_in[8];
    const float* bns_b  = (const float*)d_in[9];
    const float* w_gama = (const float*)d_in[10];
    const float* bng_s  = (const float*)d_in[11];
    const float* bng_b  = (const float*)d_in[12];
    float* out = (float*)d_out;

    char* ws = (char*)d_ws;
    // [0,32MB): conv partials pc; after k_reduce the region is reused:
    //   Opart @ 16MB (16 MB, k_attn partials)
    float*          pc    = (float*)ws;                                 // [4][8192][256]
    float*          Opart = (float*)(ws + 16u * 1024 * 1024);           // [4][8][1024][128]
    unsigned short* y     = (unsigned short*)(ws + 32u * 1024 * 1024);  // 4 MB
    unsigned short* P     = (unsigned short*)(ws + 36u * 1024 * 1024);  // 4 MB
    unsigned short* G     = (unsigned short*)(ws + 40u * 1024 * 1024);  // 2 MB
    unsigned short* w1s   = (unsigned short*)(ws + 44u * 1024 * 1024);  // 2 MB

    k_wprep <<<dim3(512),      256, 0, stream>>>(w1, w1s);
    k_conv1 <<<dim3(64, 4),    512, 0, stream>>>(x, w1s, pc);
    k_reduce<<<dim3(2048),     256, 0, stream>>>(pc, bn1_s, bn1_b, y);
    k_proj3 <<<dim3(6, 128),   256, 0, stream>>>(y, w_fai, w_sit, w_gama,
                                                 bnf_s, bnf_b, bns_s, bns_b,
                                                 bng_s, bng_b, P, G);
    k_attn  <<<dim3(16, 32),   256, 0, stream>>>(P, G, Opart);
    k_up    <<<dim3(256, 8),   256, 0, stream>>>(Opart, out);
}

// Round 7
// 471.787 us; speedup vs baseline: 1.0801x; 1.0203x over previous
//
#include <hip/hip_runtime.h>

typedef __attribute__((ext_vector_type(8))) short short8_t;
typedef __attribute__((ext_vector_type(4))) float float4_t;

__device__ __forceinline__ unsigned short f2bf(float f) {
    unsigned int u = __float_as_uint(f);
    return (unsigned short)((u + 0x7FFFu + ((u >> 16) & 1u)) >> 16);
}
__device__ __forceinline__ unsigned int pkbf(float a, float b) {
    return (unsigned int)f2bf(a) | ((unsigned int)f2bf(b) << 16);
}

// ---------------------------------------------------------------------------
// K0: one-shot w1 fp32 -> bf16 ([256][4096] row-major).
// ---------------------------------------------------------------------------
__global__ __launch_bounds__(256) void k_wprep(
    const float* __restrict__ w1, unsigned short* __restrict__ w1s)
{
    const int id = blockIdx.x * 256 + threadIdx.x;   // 131072, 8 floats each
    const float4* s = (const float4*)(w1 + id * 8);
    float4 a = s[0], b = s[1];
    int4 o;
    o.x = pkbf(a.x, a.y); o.y = pkbf(a.z, a.w);
    o.z = pkbf(b.x, b.y); o.w = pkbf(b.z, b.w);
    *(int4*)(w1s + id * 8) = o;
}

// ---------------------------------------------------------------------------
// K1: conv1 implicit GEMM — PROVEN 512-thread structure (128M x 256N, BK=32,
// split-K x4, 8 waves 2m x 4n, reg prefetch-1). B operand is pre-converted
// bf16 (w1s): B staging is pure int4 copies (no per-iter fp32->bf16 VALU).
// A-LDS XOR swizzle on k-slot, matching fragment read.
// Best verified configuration of this session: 473.8 us total.
// ---------------------------------------------------------------------------
__global__ __launch_bounds__(512, 2) void k_conv1(
    const float* __restrict__ x, const unsigned short* __restrict__ w1s,
    float* __restrict__ part)
{
    __shared__ unsigned short At[128 * 40];
    __shared__ unsigned short Bt[256 * 40];
    const int tid = threadIdx.x;
    const int mt = blockIdx.x, kc = blockIdx.y;
    const int m0 = mt * 128;
    const int bi = mt >> 3;
    const int oh0 = (mt & 7) * 4;
    const int lane = tid & 63, wid = tid >> 6;
    const int wm = wid & 1, wn = wid >> 1;          // 2 x 4 waves
    const int quad = lane >> 4, r16 = lane & 15;
    const bool isA = tid < 256;
    const int tA = tid & 255;
    const int rA = tA >> 4, segA = tA & 15;
    const int ohl = rA >> 2, khl = rA & 3;
    const int rowA = ohl * 32 + segA * 2;
    const int koffA = (khl ^ (segA & 3)) * 8;       // swizzled k-slot (shorts)
    const int kbase = kc * 1024;
    float4_t acc[4][4] = {};
    float4 ra[4];   // A prefetch regs (fp32 x-patches)
    int4 rb[4];     // B prefetch regs (bf16 w1s rows)

    // prefetch iter 0
    if (isA) {
        const int ic = kbase >> 6, kh0 = (kbase >> 3) & 7;
        const int xr = (oh0 + ohl) * 8 + kh0 + khl;
        const float4* s4 = (const float4*)(x + (((bi * 64 + ic) * 256 + xr) * 256 + segA * 16));
        ra[0] = s4[0]; ra[1] = s4[1]; ra[2] = s4[2]; ra[3] = s4[3];
    } else {
        #pragma unroll
        for (int l = 0; l < 4; ++l) {
            const int slot = l * 256 + tA;
            const int row = slot >> 2, p = slot & 3;
            rb[l] = *(const int4*)(w1s + row * 4096 + kbase + p * 8);
        }
    }

    for (int it = 0; it < 32; ++it) {
        // ---- commit prefetched regs to LDS ----
        if (isA) {
            int4 p0, p1;
            p0.x = pkbf(ra[0].x, ra[0].y); p0.y = pkbf(ra[0].z, ra[0].w);
            p0.z = pkbf(ra[1].x, ra[1].y); p0.w = pkbf(ra[1].z, ra[1].w);
            p1.x = pkbf(ra[2].x, ra[2].y); p1.y = pkbf(ra[2].z, ra[2].w);
            p1.z = pkbf(ra[3].x, ra[3].y); p1.w = pkbf(ra[3].z, ra[3].w);
            *(int4*)&At[rowA * 40 + koffA] = p0;
            *(int4*)&At[(rowA + 1) * 40 + koffA] = p1;
        } else {
            #pragma unroll
            for (int l = 0; l < 4; ++l) {
                const int slot = l * 256 + tA;
                const int row = slot >> 2, p = slot & 3;
                *(int4*)&Bt[row * 40 + p * 8] = rb[l];
            }
        }
        __syncthreads();
        // ---- issue next iter's global loads (overlap with MFMA below) ----
        if (it + 1 < 32) {
            const int k0 = kbase + (it + 1) * 32;
            if (isA) {
                const int ic = k0 >> 6, kh0 = (k0 >> 3) & 7;
                const int xr = (oh0 + ohl) * 8 + kh0 + khl;
                const float4* s4 = (const float4*)(x + (((bi * 64 + ic) * 256 + xr) * 256 + segA * 16));
                ra[0] = s4[0]; ra[1] = s4[1]; ra[2] = s4[2]; ra[3] = s4[3];
            } else {
                #pragma unroll
                for (int l = 0; l < 4; ++l) {
                    const int slot = l * 256 + tA;
                    const int row = slot >> 2, p = slot & 3;
                    rb[l] = *(const int4*)(w1s + row * 4096 + k0 + p * 8);
                }
            }
        }
        // ---- MFMA phase ----
        short8_t aF[4], bF[4];
        #pragma unroll
        for (int i = 0; i < 4; ++i) {
            const int R = wm * 64 + i * 16 + r16;
            aF[i] = *(const short8_t*)&At[R * 40 + (quad ^ ((r16 >> 1) & 3)) * 8];
        }
        #pragma unroll
        for (int j = 0; j < 4; ++j)
            bF[j] = *(const short8_t*)&Bt[(wn * 64 + j * 16 + r16) * 40 + quad * 8];
        #pragma unroll
        for (int i = 0; i < 4; ++i)
            #pragma unroll
            for (int j = 0; j < 4; ++j)
                acc[i][j] = __builtin_amdgcn_mfma_f32_16x16x32_bf16(aF[i], bF[j], acc[i][j], 0, 0, 0);
        __syncthreads();
    }
    float* pp = part + ((size_t)kc << 21);
    #pragma unroll
    for (int i = 0; i < 4; ++i) {
        const int mg = m0 + wm * 64 + i * 16 + quad * 4;
        #pragma unroll
        for (int j = 0; j < 4; ++j) {
            const int ng = wn * 64 + j * 16 + r16;
            #pragma unroll
            for (int r = 0; r < 4; ++r)
                pp[(mg + r) * 256 + ng] = acc[i][j][r];
        }
    }
}

// ---------------------------------------------------------------------------
// K1b: reduce 4 split-K partials + BN + ReLU -> y bf16 [8192,256].
// ---------------------------------------------------------------------------
__global__ __launch_bounds__(256, 4) void k_reduce(
    const float* __restrict__ part, const float* __restrict__ s1,
    const float* __restrict__ b1, unsigned short* __restrict__ y)
{
    const int id = blockIdx.x * 256 + threadIdx.x;   // 0..524287 float4 slots
    const int c4 = id & 63;
    const float4* p = (const float4*)part + id;
    float4 a = p[0], b = p[524288], c = p[1048576], d = p[1572864];
    float4 s = ((const float4*)s1)[c4], bb = ((const float4*)b1)[c4];
    float vx = fmaxf((a.x + b.x + c.x + d.x) * s.x + bb.x, 0.f);
    float vy = fmaxf((a.y + b.y + c.y + d.y) * s.y + bb.y, 0.f);
    float vz = fmaxf((a.z + b.z + c.z + d.z) * s.z + bb.z, 0.f);
    float vw = fmaxf((a.w + b.w + c.w + d.w) * s.w + bb.w, 0.f);
    int2 o; o.x = pkbf(vx, vy); o.y = pkbf(vz, vw);
    ((int2*)y)[id] = o;
}

// ---------------------------------------------------------------------------
// K2: fused fai/sit/gama projections.
// nt<4 -> P bf16 [8192,256] (cols 0-127 fai, 128-255 sit);
// nt>=4 -> G bf16 [8,128,1024] (transposed, AV GEMM B-operand).
// ---------------------------------------------------------------------------
__global__ __launch_bounds__(256, 2) void k_proj3(
    const unsigned short* __restrict__ y,
    const float* __restrict__ w_fai, const float* __restrict__ w_sit,
    const float* __restrict__ w_gama,
    const float* __restrict__ fs, const float* __restrict__ fb,
    const float* __restrict__ ss, const float* __restrict__ sb,
    const float* __restrict__ gs, const float* __restrict__ gb,
    unsigned short* __restrict__ P, unsigned short* __restrict__ G)
{
    __shared__ unsigned short At[64 * 40];
    __shared__ unsigned short Bt[64 * 40];
    const int tid = threadIdx.x;
    const int nt = blockIdx.x, mt = blockIdx.y;
    const int m0 = mt * 64;
    const float *W, *S, *Bb;
    if (nt < 2)      { W = w_fai;  S = fs; Bb = fb; }
    else if (nt < 4) { W = w_sit;  S = ss; Bb = sb; }
    else             { W = w_gama; S = gs; Bb = gb; }
    const int roff = (nt * 64) & 127;
    const int lane = tid & 63, wid = tid >> 6;
    const int wm = wid & 1, wn = wid >> 1;
    const int quad = lane >> 4, r16 = lane & 15;
    float4_t acc[2][2] = {};

    for (int k0 = 0; k0 < 256; k0 += 32) {
        {   // A: y tile 64x32 bf16, direct copy
            const int row = tid >> 2, pp = tid & 3;
            *(int4*)&At[row * 40 + pp * 8] =
                *(const int4*)(y + (m0 + row) * 256 + k0 + pp * 8);
        }
        #pragma unroll
        for (int l = 0; l < 2; ++l) {   // B: W tile 64x32 fp32 -> bf16
            const int slot = l * 256 + tid;
            const int row = slot >> 3, pp = slot & 7;
            float4 v = *(const float4*)(W + (roff + row) * 256 + k0 + pp * 4);
            int2 wv; wv.x = pkbf(v.x, v.y); wv.y = pkbf(v.z, v.w);
            *(int2*)&Bt[row * 40 + pp * 4] = wv;
        }
        __syncthreads();
        short8_t aF[2], bF[2];
        #pragma unroll
        for (int i = 0; i < 2; ++i)
            aF[i] = *(const short8_t*)&At[(wm * 32 + i * 16 + r16) * 40 + quad * 8];
        #pragma unroll
        for (int j = 0; j < 2; ++j)
            bF[j] = *(const short8_t*)&Bt[(wn * 32 + j * 16 + r16) * 40 + quad * 8];
        #pragma unroll
        for (int i = 0; i < 2; ++i)
            #pragma unroll
            for (int j = 0; j < 2; ++j)
                acc[i][j] = __builtin_amdgcn_mfma_f32_16x16x32_bf16(aF[i], bF[j], acc[i][j], 0, 0, 0);
        __syncthreads();
    }
    #pragma unroll
    for (int i = 0; i < 2; ++i) {
        const int mg = m0 + wm * 32 + i * 16 + quad * 4;
        #pragma unroll
        for (int j = 0; j < 2; ++j) {
            const int nl = wn * 32 + j * 16 + r16;
            const float sc = S[roff + nl], bc = Bb[roff + nl];
            if (nt < 4) {
                const int col = nt * 64 + nl;
                #pragma unroll
                for (int r = 0; r < 4; ++r) {
                    float v = fmaxf(acc[i][j][r] * sc + bc, 0.f);
                    P[(mg + r) * 256 + col] = f2bf(v);
                }
            } else {
                const int c = roff + nl;
                #pragma unroll
                for (int r = 0; r < 4; ++r) {
                    float v = fmaxf(acc[i][j][r] * sc + bc, 0.f);
                    const int sp = mg + r;
                    G[((sp >> 10) * 128 + c) * 1024 + (sp & 1023)] = f2bf(v);
                }
            }
        }
    }
}

// ---------------------------------------------------------------------------
// K3+K4 fused: k_attn. Per block: 64 n-rows x 128 ch, m-range = kc*256..+256
// (2 subtiles of 128). GEMM1: S = fai^T sit (K=128, single LDS tile, BK=128).
// sigmoid in registers (__expf + rcp), S -> LDS bf16 only (sf never in HBM).
// GEMM2: Opart[n,ch] += sigma(S) . G^T. Grid (16 nt, 32 = b*4+kc).
// Partials Opart[kc][8][1024][128] fp32 (same layout k_up consumes).
// ---------------------------------------------------------------------------
#define LSTR 152
__global__ __launch_bounds__(256, 2) void k_attn(
    const unsigned short* __restrict__ P, const unsigned short* __restrict__ G,
    float* __restrict__ Opart)
{
    __shared__ unsigned short At[64 * LSTR];    // fai tile [64 n][128 c]
    __shared__ unsigned short Bt[128 * LSTR];   // sit tile, then G tile
    __shared__ unsigned short Sl[64 * LSTR];    // sigma(S) [64 n][128 m]
    const int tid = threadIdx.x;
    const int nt = blockIdx.x, zz = blockIdx.y;
    const int b = zz >> 2, kc = zz & 3;
    const int n0 = nt * 64;
    const int base = b * 1024;
    const int lane = tid & 63, wid = tid >> 6;
    const int wm = wid & 1, wn = wid >> 1;
    const int quad = lane >> 4, r16 = lane & 15;
    float4_t acc2[2][4] = {};

    // stage fai tile once (reused by both m-subtiles)
    #pragma unroll
    for (int l = 0; l < 4; ++l) {
        const int slot = l * 256 + tid;
        const int row = slot >> 4, p = slot & 15;
        *(int4*)&At[row * LSTR + p * 8] =
            *(const int4*)(P + (base + n0 + row) * 256 + p * 8);
    }
    for (int ms = 0; ms < 2; ++ms) {
        const int m1 = kc * 256 + ms * 128;
        // stage sit tile [128 m][128 c]
        #pragma unroll
        for (int l = 0; l < 8; ++l) {
            const int slot = l * 256 + tid;
            const int row = slot >> 4, p = slot & 15;
            *(int4*)&Bt[row * LSTR + p * 8] =
                *(const int4*)(P + (base + m1 + row) * 256 + 128 + p * 8);
        }
        __syncthreads();
        // GEMM1: S[n,m], wave tile 32(n) x 64(m)
        float4_t acc1[2][4] = {};
        #pragma unroll
        for (int c = 0; c < 4; ++c) {
            short8_t aF[2], bF[4];
            #pragma unroll
            for (int i = 0; i < 2; ++i)
                aF[i] = *(const short8_t*)&At[(wm * 32 + i * 16 + r16) * LSTR + c * 32 + quad * 8];
            #pragma unroll
            for (int j = 0; j < 4; ++j)
                bF[j] = *(const short8_t*)&Bt[(wn * 64 + j * 16 + r16) * LSTR + c * 32 + quad * 8];
            #pragma unroll
            for (int i = 0; i < 2; ++i)
                #pragma unroll
                for (int j = 0; j < 4; ++j)
                    acc1[i][j] = __builtin_amdgcn_mfma_f32_16x16x32_bf16(aF[i], bF[j], acc1[i][j], 0, 0, 0);
        }
        __syncthreads();   // Bt(sit) reads done; prev-ms Sl reads long done
        // sigmoid -> Sl (LDS only)
        #pragma unroll
        for (int i = 0; i < 2; ++i) {
            const int nl = wm * 32 + i * 16 + quad * 4;
            #pragma unroll
            for (int j = 0; j < 4; ++j) {
                const int ml = wn * 64 + j * 16 + r16;
                #pragma unroll
                for (int r = 0; r < 4; ++r) {
                    const float xv = acc1[i][j][r];
                    const float e = __expf(-xv);
                    const float v = __builtin_amdgcn_rcpf(1.0f + e);
                    Sl[(nl + r) * LSTR + ml] = f2bf(v);
                }
            }
        }
        // restage Bt with G tile [128 ch][128 m]
        #pragma unroll
        for (int l = 0; l < 8; ++l) {
            const int slot = l * 256 + tid;
            const int row = slot >> 4, p = slot & 15;
            *(int4*)&Bt[row * LSTR + p * 8] =
                *(const int4*)(G + (b * 128 + row) * 1024 + m1 + p * 8);
        }
        __syncthreads();   // Sl + G visible
        // GEMM2: O[n,ch] += Sl . G^T, wave tile 32(n) x 64(ch)
        #pragma unroll
        for (int c = 0; c < 4; ++c) {
            short8_t aF[2], bF[4];
            #pragma unroll
            for (int i = 0; i < 2; ++i)
                aF[i] = *(const short8_t*)&Sl[(wm * 32 + i * 16 + r16) * LSTR + c * 32 + quad * 8];
            #pragma unroll
            for (int j = 0; j < 4; ++j)
                bF[j] = *(const short8_t*)&Bt[(wn * 64 + j * 16 + r16) * LSTR + c * 32 + quad * 8];
            #pragma unroll
            for (int i = 0; i < 2; ++i)
                #pragma unroll
                for (int j = 0; j < 4; ++j)
                    acc2[i][j] = __builtin_amdgcn_mfma_f32_16x16x32_bf16(aF[i], bF[j], acc2[i][j], 0, 0, 0);
        }
        __syncthreads();   // before next ms overwrites Bt / Sl
    }
    float* op = Opart + (size_t)kc * 1048576 + (size_t)b * 131072;
    #pragma unroll
    for (int i = 0; i < 2; ++i) {
        const int nl = n0 + wm * 32 + i * 16 + quad * 4;
        #pragma unroll
        for (int j = 0; j < 4; ++j) {
            const int ch = wn * 64 + j * 16 + r16;
            #pragma unroll
            for (int r = 0; r < 4; ++r)
                op[(nl + r) * 128 + ch] = acc2[i][j][r];
        }
    }
}

// ---------------------------------------------------------------------------
// K5: sum 4 O-partials + bilinear x8 upsample (align_corners).
// ---------------------------------------------------------------------------
__global__ __launch_bounds__(256, 2) void k_up(
    const float* __restrict__ Opart, float* __restrict__ out)
{
    __shared__ float l0[32 * 136];
    __shared__ float l1[32 * 136];
    const int tid = threadIdx.x;
    const int yb = blockIdx.x, b = blockIdx.y;
    const float sc = 31.0f / 255.0f;
    const float fy = yb * sc;
    const int y0 = (int)fy;
    const float wy = fy - (float)y0;
    const int y1 = (y0 + 1 < 32) ? y0 + 1 : 31;
    const float4* r0 = (const float4*)(Opart + (size_t)b * 131072 + y0 * 4096);
    const float4* r1 = (const float4*)(Opart + (size_t)b * 131072 + y1 * 4096);
    #pragma unroll
    for (int j = 0; j < 4; ++j) {
        const int id = j * 256 + tid;       // 0..1023 float4 chunks of a row
        const int xs = id >> 5, c4 = id & 31;
        float4 a0 = r0[id], a1 = r1[id];
        #pragma unroll
        for (int kc = 1; kc < 4; ++kc) {
            float4 t0 = r0[id + kc * 262144], t1 = r1[id + kc * 262144];
            a0.x += t0.x; a0.y += t0.y; a0.z += t0.z; a0.w += t0.w;
            a1.x += t1.x; a1.y += t1.y; a1.z += t1.z; a1.w += t1.w;
        }
        *(float4*)(l0 + xs * 136 + c4 * 4) = a0;
        *(float4*)(l1 + xs * 136 + c4 * 4) = a1;
    }
    __syncthreads();
    const float fx = tid * sc;
    const int x0 = (int)fx;
    const float wx = fx - (float)x0;
    const int x1 = (x0 + 1 < 32) ? x0 + 1 : 31;
    const float w00 = (1.f - wy) * (1.f - wx), w01 = (1.f - wy) * wx;
    const float w10 = wy * (1.f - wx), w11 = wy * wx;
    const float* a = l0 + x0 * 136;
    const float* bq = l0 + x1 * 136;
    const float* c = l1 + x0 * 136;
    const float* d = l1 + x1 * 136;
    float* op = out + (size_t)b * 8388608 + yb * 256 + tid;
    #pragma unroll 4
    for (int ch = 0; ch < 128; ++ch)
        op[ch * 65536] = w00 * a[ch] + w01 * bq[ch] + w10 * c[ch] + w11 * d[ch];
}

extern "C" void kernel_launch(void* const* d_in, const int* in_sizes, int n_in,
                              void* d_out, int out_size, void* d_ws, size_t ws_size,
                              hipStream_t stream) {
    (void)in_sizes; (void)n_in; (void)out_size; (void)ws_size;
    const float* x      = (const float*)d_in[0];
    const float* w1     = (const float*)d_in[1];
    const float* bn1_s  = (const float*)d_in[2];
    const float* bn1_b  = (const float*)d_in[3];
    const float* w_fai  = (const float*)d_in[4];
    const float* bnf_s  = (const float*)d_in[5];
    const float* bnf_b  = (const float*)d_in[6];
    const float* w_sit  = (const float*)d_in[7];
    const float* bns_s  = (const float*)d_in[8];
    const float* bns_b  = (const float*)d_in[9];
    const float* w_gama = (const float*)d_in[10];
    const float* bng_s  = (const float*)d_in[11];
    const float* bng_b  = (const float*)d_in[12];
    float* out = (float*)d_out;

    char* ws = (char*)d_ws;
    // [0,32MB): conv partials pc; after k_reduce the region is reused:
    //   Opart @ 16MB (16 MB, k_attn partials)
    float*          pc    = (float*)ws;                                 // [4][8192][256]
    float*          Opart = (float*)(ws + 16u * 1024 * 1024);           // [4][8][1024][128]
    unsigned short* y     = (unsigned short*)(ws + 32u * 1024 * 1024);  // 4 MB
    unsigned short* P     = (unsigned short*)(ws + 36u * 1024 * 1024);  // 4 MB
    unsigned short* G     = (unsigned short*)(ws + 40u * 1024 * 1024);  // 2 MB
    unsigned short* w1s   = (unsigned short*)(ws + 44u * 1024 * 1024);  // 2 MB

    k_wprep <<<dim3(512),      256, 0, stream>>>(w1, w1s);
    k_conv1 <<<dim3(64, 4),    512, 0, stream>>>(x, w1s, pc);
    k_reduce<<<dim3(2048),     256, 0, stream>>>(pc, bn1_s, bn1_b, y);
    k_proj3 <<<dim3(6, 128),   256, 0, stream>>>(y, w_fai, w_sit, w_gama,
                                                 bnf_s, bnf_b, bns_s, bns_b,
                                                 bng_s, bng_b, P, G);
    k_attn  <<<dim3(16, 32),   256, 0, stream>>>(P, G, Opart);
    k_up    <<<dim3(256, 8),   256, 0, stream>>>(Opart, out);
}